// Round 6
// baseline (222.797 us; speedup 1.0000x reference)
//
#include <hip/hip_runtime.h>
#include <math.h>

#define L_ 2
#define BAT_ 32
#define A_ 64
#define B_ 1024
#define D_ 128
#define NBITS_ 1024
#define NW 32                 // u32 words per code (1024 bits)
#define NQROWS (L_*BAT_*A_)   // 4096
#define NDROWS (L_*BAT_*B_)   // 65536
#define NROWS (NQROWS + NDROWS) // 69632

#define TM 128                // rows per block
#define TN 128                // bits per block
#define KH 32                 // K staged in quarters
// LDS row: [hi 0..31 | lo 32..63 | pad 8] bf16 -> 72 elems = 36 dwords.
// 36 ≡ 4 (mod 32): frag-read bank group = (tn+quad)%8 -> uniform 8 lanes/group
// = the b128 floor (no extra conflicts). 72%8==0 keeps 16-B b128 alignment.
#define RS 72

typedef __bf16 bf16x4 __attribute__((ext_vector_type(4)));
typedef __bf16 bf16x8 __attribute__((ext_vector_type(8)));
typedef float  f32x4  __attribute__((ext_vector_type(4)));

// -------- Stage 0: presplit r into bf16 hi|lo (runs once, ~0.5 MB ws) ------
// rsp row (per bit): [hi 0..127 | lo 128..255] bf16.
__global__ __launch_bounds__(256) void split_r_kernel(
    const float* __restrict__ r, __bf16* __restrict__ rsp)
{
    int tid = blockIdx.x * 256 + threadIdx.x;   // 32768 threads
    int f = tid * 4;                            // [0, 131072)
    int row = f >> 7, cc = f & 127;
    float4 v = *(const float4*)(r + f);
    bf16x4 hi, lo;
    hi[0] = (__bf16)v.x; hi[1] = (__bf16)v.y;
    hi[2] = (__bf16)v.z; hi[3] = (__bf16)v.w;
    lo[0] = (__bf16)(v.x - (float)hi[0]);
    lo[1] = (__bf16)(v.y - (float)hi[1]);
    lo[2] = (__bf16)(v.z - (float)hi[2]);
    lo[3] = (__bf16)(v.w - (float)hi[3]);
    *(bf16x4*)(&rsp[(size_t)row * 256 + cc])       = hi;
    *(bf16x4*)(&rsp[(size_t)row * 256 + 128 + cc]) = lo;
}

// ---------------- Stage 1: LSH sign-hash (bf16-split MFMA + ballot pack) ----
// grid (544, 8), block 256 = 4 waves (2x2 of 64x64 wave tiles).
// Per k-quarter: hoisted frags (A-hi/lo, B-hi shared by hh+lh, then B-lo for hl).
// Writes codes TRANSPOSED: codes_t[word][row] for stage-2 coalescing.
__global__ __launch_bounds__(256, 3) void hash_kernel(
    const float* __restrict__ qe, const float* __restrict__ de,
    const __bf16* __restrict__ rsp, unsigned int* __restrict__ codes_t)
{
    __shared__ __align__(16) __bf16 As[TM * RS];   // 18432 B
    __shared__ __align__(16) __bf16 Bs[TN * RS];   // 18432 B (36.9 KB total)

    const int t = threadIdx.x;
    const int row0 = blockIdx.x * TM;   // 4096 % 128 == 0: no q/d straddle
    const int bit0 = blockIdx.y * TN;

    const float* abase = (row0 < NQROWS) ? (qe + (size_t)row0 * D_)
                                         : (de + (size_t)(row0 - NQROWS) * D_);

    const int wv   = t >> 6;          // wave 0..3
    const int lane = t & 63;
    const int quad = lane >> 4;       // 0..3
    const int col  = lane & 15;       // 0..15
    const int wrow = (wv >> 1) * 64;
    const int wbit = (wv & 1) * 64;

    f32x4 acc[4][4];
    #pragma unroll
    for (int ti = 0; ti < 4; ++ti)
        #pragma unroll
        for (int tj = 0; tj < 4; ++tj)
            acc[ti][tj] = (f32x4){0.f, 0.f, 0.f, 0.f};

    #pragma unroll
    for (int ks = 0; ks < D_; ks += KH) {
        if (ks) __syncthreads();
        // --- A: 128x32 fp32 -> bf16 hi|lo split (4 float4/thread) ---
        #pragma unroll
        for (int i = 0; i < 4; ++i) {
            int f = (t + i * 256) * 4;      // [0, 4096)
            int rr = f >> 5, cc = f & 31;
            float4 v = *(const float4*)(abase + (size_t)rr * D_ + ks + cc);
            bf16x4 hi, lo;
            hi[0] = (__bf16)v.x; hi[1] = (__bf16)v.y;
            hi[2] = (__bf16)v.z; hi[3] = (__bf16)v.w;
            lo[0] = (__bf16)(v.x - (float)hi[0]);
            lo[1] = (__bf16)(v.y - (float)hi[1]);
            lo[2] = (__bf16)(v.z - (float)hi[2]);
            lo[3] = (__bf16)(v.w - (float)hi[3]);
            *(bf16x4*)(&As[rr * RS + cc])      = hi;
            *(bf16x4*)(&As[rr * RS + 32 + cc]) = lo;
        }
        // --- B: pure bf16x8 copy from presplit rsp (4 per thread) ---
        #pragma unroll
        for (int i = 0; i < 4; ++i) {
            int f = (t + i * 256) * 8;      // [0, 8192)
            int rr = f >> 6, cc = f & 63;   // 64 bf16/row = hi32|lo32
            int src = (cc < 32) ? (ks + cc) : (96 + ks + cc); // lo at 128+
            bf16x8 v = *(const bf16x8*)(&rsp[(size_t)(bit0 + rr) * 256 + src]);
            *(bf16x8*)(&Bs[rr * RS + cc]) = v;
        }
        __syncthreads();

        // --- hoisted fragments, 48 MFMA per quarter ---
        bf16x8 afhi[4], aflo[4], bfr[4];
        #pragma unroll
        for (int ti = 0; ti < 4; ++ti) {
            const __bf16* p = &As[(wrow + ti * 16 + col) * RS + quad * 8];
            afhi[ti] = *(const bf16x8*)(p);
            aflo[ti] = *(const bf16x8*)(p + 32);
        }
        #pragma unroll
        for (int tj = 0; tj < 4; ++tj)
            bfr[tj] = *(const bf16x8*)(
                &Bs[(wbit + tj * 16 + col) * RS + quad * 8]);
        #pragma unroll
        for (int ti = 0; ti < 4; ++ti)
            #pragma unroll
            for (int tj = 0; tj < 4; ++tj)
                acc[ti][tj] = __builtin_amdgcn_mfma_f32_16x16x32_bf16(
                    afhi[ti], bfr[tj], acc[ti][tj], 0, 0, 0);   // hi*hi
        #pragma unroll
        for (int ti = 0; ti < 4; ++ti)
            #pragma unroll
            for (int tj = 0; tj < 4; ++tj)
                acc[ti][tj] = __builtin_amdgcn_mfma_f32_16x16x32_bf16(
                    aflo[ti], bfr[tj], acc[ti][tj], 0, 0, 0);   // lo*hi
        #pragma unroll
        for (int tj = 0; tj < 4; ++tj)
            bfr[tj] = *(const bf16x8*)(
                &Bs[(wbit + tj * 16 + col) * RS + 32 + quad * 8]);
        #pragma unroll
        for (int ti = 0; ti < 4; ++ti)
            #pragma unroll
            for (int tj = 0; tj < 4; ++tj)
                acc[ti][tj] = __builtin_amdgcn_mfma_f32_16x16x32_bf16(
                    afhi[ti], bfr[tj], acc[ti][tj], 0, 0, 0);   // hi*lo
    }

    // Sign-pack via ballot; C/D layout (m89): col=lane&15, row=quad*4+reg.
    // Transposed store: codes_t[word][row].
    #pragma unroll
    for (int ti = 0; ti < 4; ++ti) {
        #pragma unroll
        for (int rg = 0; rg < 4; ++rg) {
            unsigned long long b[4];
            #pragma unroll
            for (int tj = 0; tj < 4; ++tj)
                b[tj] = __ballot(acc[ti][tj][rg] > 0.f);
            if (col < 2) {
                const int w = col;
                unsigned int lo16 = (unsigned int)(b[2 * w]     >> (16 * quad)) & 0xFFFFu;
                unsigned int hi16 = (unsigned int)(b[2 * w + 1] >> (16 * quad)) & 0xFFFFu;
                const int row = row0 + wrow + ti * 16 + quad * 4 + rg;
                const int wg  = blockIdx.y * 4 + (wv & 1) * 2 + w;
                codes_t[(size_t)wg * NROWS + row] = lo16 | (hi16 << 16);
            }
        }
    }
}

// ---------------- Stage 2: Hamming -> cos LUT -> mask -> out ----------------
// grid: 1024 blocks (l, b, 4 doc-chunks, 4 a-chunks of 16), block 256 = 1 doc.
// codes_t is word-major: all loads lane-consecutive (coalesced).
__global__ __launch_bounds__(256) void simmat_kernel(
    const unsigned int* __restrict__ codes_t,
    const int* __restrict__ qtok, const int* __restrict__ dtok,
    float* __restrict__ out)
{
    __shared__ unsigned int qc[16 * 36];  // 16 a-rows, stride 36 (b128-aligned)
    __shared__ float lut[NBITS_ + 1];
    __shared__ float qm[16];

    const int blk  = blockIdx.x;
    const int ct   = blk & 3;
    const int asub = (blk >> 2) & 3;
    const int b    = (blk >> 4) & 31;
    const int l    = blk >> 9;
    const int t    = threadIdx.x;

    for (int h = t; h <= NBITS_; h += 256)
        lut[h] = cosf((float)M_PI / (float)NBITS_ * (float)h);

    const int a0 = asub * 16;
    const int qrow0 = (l * BAT_ + b) * A_ + a0;
    // stage 16x32 query words, coalesced: idx -> (w=idx>>4, a=idx&15)
    for (int i = 0; i < 2; ++i) {
        int idx = i * 256 + t;            // [0, 512)
        int w = idx >> 4, a = idx & 15;
        qc[a * 36 + w] = codes_t[(size_t)w * NROWS + qrow0 + a];
    }
    if (t < 16) qm[t] = (qtok[b * A_ + a0 + t] != 0) ? 1.f : 0.f;
    __syncthreads();

    const int c = ct * 256 + t;
    const size_t drow = (size_t)NQROWS + (size_t)(l * BAT_ + b) * B_ + c;
    unsigned int dc[NW];
    #pragma unroll
    for (int w = 0; w < NW; ++w) dc[w] = codes_t[(size_t)w * NROWS + drow];
    const float dm = (dtok[b * B_ + c] != 0) ? 1.f : 0.f;

    float* obase = out + ((size_t)((b * L_ + l) * A_ + a0)) * B_ + c;
    #pragma unroll
    for (int ai = 0; ai < 16; ++ai) {
        int ham = 0;
        #pragma unroll
        for (int m = 0; m < 8; ++m) {
            uint4 qv = *(const uint4*)(&qc[ai * 36 + m * 4]);
            ham += __popc(qv.x ^ dc[4 * m])     + __popc(qv.y ^ dc[4 * m + 1])
                 + __popc(qv.z ^ dc[4 * m + 2]) + __popc(qv.w ^ dc[4 * m + 3]);
        }
        obase[(size_t)ai * B_] = lut[ham] * qm[ai] * dm;
    }
}

extern "C" void kernel_launch(void* const* d_in, const int* in_sizes, int n_in,
                              void* d_out, int out_size, void* d_ws, size_t ws_size,
                              hipStream_t stream) {
    const float* qe  = (const float*)d_in[0];  // [L,BAT,A,D]
    const float* de  = (const float*)d_in[1];  // [L,BAT,B,D]
    const int* qtok  = (const int*)d_in[2];    // [BAT,A]
    const int* dtok  = (const int*)d_in[3];    // [BAT,B]
    const float* r   = (const float*)d_in[4];  // [NBITS,D]
    float* out = (float*)d_out;                // [BAT,L,A,B] fp32

    // ws layout: [0, 512KB) r presplit; [512KB, +8.9MB) transposed codes
    __bf16* rsp = (__bf16*)d_ws;
    unsigned int* codes_t = (unsigned int*)((char*)d_ws + 524288);

    split_r_kernel<<<128, 256, 0, stream>>>(r, rsp);
    dim3 g1(NROWS / TM, NBITS_ / TN);
    hash_kernel<<<g1, 256, 0, stream>>>(qe, de, rsp, codes_t);
    simmat_kernel<<<L_ * BAT_ * 4 * 4, 256, 0, stream>>>(codes_t, qtok, dtok, out);
}